// Round 9
// baseline (732.053 us; speedup 1.0000x reference)
//
#include <hip/hip_runtime.h>
#include <hip/hip_cooperative_groups.h>
#include <hip/hip_fp16.h>
#include <math.h>

namespace cg = cooperative_groups;

#define NS 64
#define NV 16
#define NHS 32
#define NHV 16
#define NPB 16           // nodes per chunk in phase 1 (16 lanes/node, 256 threads)
#define WS_PAD 68        // padded row stride for Ws in LDS (breaks bank conflict)
#define WV_PAD 17

#define RANGES 32        // node ranges (one LDS den per range)
#define SPLITS 32        // edge-list splits
#define DP_STRIDE 50176  // padded per-split den stride (>= N, mult of 256)
#define MAXGRID 1024
#define BLK 256

// LDS pool carve (floats). Phase1: weights(2528) + staging(1984) = 4512.
// Phase3 lden(<=1568) aliases the pool (phases are grid.sync separated).
#define OFF_LWS 0
#define OFF_LWV 2176
#define OFF_LWA 2448
#define OFF_LS  2528
#define OFF_LV  3552
#define OFF_LF  4320
#define OFF_LP  4464
#define SMEM_FLOATS 4512

__device__ __forceinline__ float silu_f(float x){ return x * (1.0f / (1.0f + __expf(-x))); }

__device__ __forceinline__ float packh2(float a, float b){
    __half2 h = __floats2half2_rn(a, b);
    return __uint_as_float(*(unsigned*)&h);
}
__device__ __forceinline__ float2 unpackh2(float w){
    __half2 h = *(__half2*)&w;
    return __half22float2(h);
}

// ---------- device helpers shared by mega + fallback ----------
__device__ __forceinline__ void node_pack_body(
    const float* __restrict__ node_s, const float* __restrict__ node_v,
    const float* __restrict__ frame, const float* __restrict__ pos,
    float* __restrict__ pack, int N, int nbase, int cnt,
    float* lws, float* lwv, float* lwa, float* ls, float* lv, float* lf, float* lp,
    int tid)
{
    const int g = tid >> 4;
    const int l = tid & 15;
    if (g >= cnt) return;
    const int n = nbase + g;

    const float4* sg = (const float4*)(ls + g * NS);
    float d0 = 0.f, d1 = 0.f;
    #pragma unroll
    for (int k4 = 0; k4 < NS / 4; k4++){
        float4 sv = sg[k4];
        float4 w0 = *(const float4*)(lws + l * WS_PAD + k4 * 4);
        float4 w1 = *(const float4*)(lws + (l + 16) * WS_PAD + k4 * 4);
        d0 += sv.x * w0.x + sv.y * w0.y + sv.z * w0.z + sv.w * w0.w;
        d1 += sv.x * w1.x + sv.y * w1.y + sv.z * w1.z + sv.w * w1.w;
    }
    float acc = silu_f(d0) * lwa[l] + silu_f(d1) * lwa[l + 16];

    float a0 = 0.f, a1 = 0.f, a2 = 0.f;
    const float* vg = lv + g * NV * 3;
    #pragma unroll
    for (int vv = 0; vv < NV; vv++){
        float w = lwv[l * WV_PAD + vv];
        a0 += vg[vv * 3 + 0] * w;
        a1 += vg[vv * 3 + 1] * w;
        a2 += vg[vv * 3 + 2] * w;
    }
    const float* ff = lf + g * 9;
    #pragma unroll
    for (int c3 = 0; c3 < 3; c3++){
        float t = a0 * ff[c3] + a1 * ff[3 + c3] + a2 * ff[6 + c3];
        acc += silu_f(t) * lwa[NHS + l * 3 + c3];
    }

    acc += __shfl_xor(acc, 8, 16);
    acc += __shfl_xor(acc, 4, 16);
    acc += __shfl_xor(acc, 2, 16);
    acc += __shfl_xor(acc, 1, 16);

    if (l < 2){
        const float* ps = lp + g * 3;
        float4 o;
        if (l == 0){
            o = make_float4(acc, packh2(ff[0], ff[1]), packh2(ff[2], ff[3]), packh2(ff[4], ff[5]));
        } else {
            o = make_float4(packh2(ff[6], ff[7]), packh2(ff[8], ps[0]), packh2(ps[1], ps[2]), 0.0f);
        }
        ((float4*)(pack + (size_t)n * 8))[l] = o;
    }
}

__device__ __forceinline__ float edge_raw_exp(
    const float* __restrict__ packA, const float* __restrict__ packB,
    int i0, int i1,
    float w112, float w113, float w114, float w163, float w164, float w165)
{
    const float4* pa = (const float4*)(packA + (size_t)i0 * 8);
    const float4* pb = (const float4*)(packB + (size_t)i1 * 8);
    float4 a0 = pa[0], a1 = pa[1];
    float4 b0 = pb[0], b1 = pb[1];

    float2 t;
    t = unpackh2(a0.y); float af0 = t.x, af1 = t.y;
    t = unpackh2(a0.z); float af2 = t.x, af3 = t.y;
    t = unpackh2(a0.w); float af4 = t.x, af5 = t.y;
    t = unpackh2(a1.x); float af6 = t.x, af7 = t.y;
    t = unpackh2(a1.y); float af8 = t.x, ap0 = t.y;
    t = unpackh2(a1.z); float ap1 = t.x, ap2 = t.y;
    t = unpackh2(b0.y); float bf0 = t.x, bf1 = t.y;
    t = unpackh2(b0.z); float bf2 = t.x, bf3 = t.y;
    t = unpackh2(b0.w); float bf4 = t.x, bf5 = t.y;
    t = unpackh2(b1.x); float bf6 = t.x, bf7 = t.y;
    t = unpackh2(b1.y); float bf8 = t.x, bp0 = t.y;
    t = unpackh2(b1.z); float bp1 = t.x, bp2 = t.y;

    float d0 = bp0 - ap0, d1 = bp1 - ap1, d2 = bp2 - ap2;
    float pdf0 = d0*af0 + d1*af3 + d2*af6;
    float pdf1 = d0*af1 + d1*af4 + d2*af7;
    float pdf2 = d0*af2 + d1*af5 + d2*af8;
    float pdt0 = -(d0*bf0 + d1*bf3 + d2*bf6);
    float pdt1 = -(d0*bf1 + d1*bf4 + d2*bf7);
    float pdt2 = -(d0*bf2 + d1*bf5 + d2*bf8);

    float r = a0.x + b0.x;
    r += silu_f(pdf0) * w112 + silu_f(pdf1) * w113 + silu_f(pdf2) * w114;
    r += silu_f(pdt0) * w163 + silu_f(pdt1) * w164 + silu_f(pdt2) * w165;
    return __expf(r);
}

// ================= cooperative mega-kernel (grid-size agnostic) =================
__global__ __launch_bounds__(BLK, 4) void mega_kernel(
    const float* __restrict__ from_s, const float* __restrict__ from_v,
    const float* __restrict__ to_s, const float* __restrict__ to_v,
    const float* __restrict__ from_fr, const float* __restrict__ to_fr,
    const float* __restrict__ from_p, const float* __restrict__ to_p,
    const float* __restrict__ Wfs, const float* __restrict__ Wts,
    const float* __restrict__ Wfv, const float* __restrict__ Wtv,
    const float* __restrict__ Wattn, const int* __restrict__ idx,
    float* __restrict__ packA, float* __restrict__ packB,
    float* __restrict__ ex, float* __restrict__ den_part,
    float* __restrict__ den, unsigned short* __restrict__ i016,
    float* __restrict__ out, int N, int E)
{
    __shared__ float smem[SMEM_FLOATS];   // 17.6 KB, aliased per phase
    float* lws = smem + OFF_LWS;
    float* lwv = smem + OFF_LWV;
    float* lwa = smem + OFF_LWA;
    float* ls  = smem + OFF_LS;
    float* lv  = smem + OFF_LV;
    float* lf  = smem + OFF_LF;
    float* lp  = smem + OFF_LP;
    float* lden = smem;                    // phase 3 alias

    cg::grid_group grid = cg::this_grid();
    const int tid = threadIdx.x;
    const int nthreads = gridDim.x * BLK;

    // ---------------- Phase 1: node packs (side interleaved) ----------------
    {
        const int side   = blockIdx.x & 1;
        const int blocal = blockIdx.x >> 1;
        const int bstride = gridDim.x >> 1;          // grid is even
        const float* node_s = side ? to_s  : from_s;
        const float* node_v = side ? to_v  : from_v;
        const float* frame  = side ? to_fr : from_fr;
        const float* pos    = side ? to_p  : from_p;
        const float* Wsp    = side ? Wts   : Wfs;
        const float* Wvp    = side ? Wtv   : Wfv;
        const int    s_off  = side ? 32 : 0;
        const int    v_off  = side ? 115 : 64;
        float*       pack   = side ? packB : packA;

        for (int i = tid; i < NHS * NS; i += BLK) lws[(i / NS) * WS_PAD + (i % NS)] = Wsp[i];
        if (tid < NHV * NV) lwv[(tid / NV) * WV_PAD + (tid % NV)] = Wvp[tid];
        if (tid < NHS) lwa[tid] = Wattn[s_off + tid];
        if (tid < NHV * 3) lwa[NHS + tid] = Wattn[v_off + tid];

        const int nchunks = (N + NPB - 1) / NPB;
        for (int c = blocal; c < nchunks; c += bstride){
            const int nbase = c * NPB;
            const int cnt = min(NPB, N - nbase);
            __syncthreads();
            {
                const float4* sp = (const float4*)(node_s + (size_t)nbase * NS);
                if (tid < cnt * (NS / 4)) ((float4*)ls)[tid] = sp[tid];
                const float4* vp = (const float4*)(node_v + (size_t)nbase * NV * 3);
                if (tid < cnt * (NV * 3 / 4)) ((float4*)lv)[tid] = vp[tid];
                if (tid < cnt * 9) lf[tid] = frame[(size_t)nbase * 9 + tid];
                if (tid < cnt * 3) lp[tid] = pos[(size_t)nbase * 3 + tid];
            }
            __syncthreads();
            node_pack_body(node_s, node_v, frame, pos, pack, N, nbase, cnt,
                           lws, lwv, lwa, ls, lv, lf, lp, tid);
        }
    }
    __threadfence();
    grid.sync();

    // ---------------- Phase 2: edge raw -> exp ----------------
    {
        const float w112 = Wattn[112], w113 = Wattn[113], w114 = Wattn[114];
        const float w163 = Wattn[163], w164 = Wattn[164], w165 = Wattn[165];
        for (int e = blockIdx.x * BLK + tid; e < E; e += nthreads){
            int i0 = idx[e];
            int i1 = idx[E + e];
            ex[e] = edge_raw_exp(packA, packB, i0, i1, w112, w113, w114, w163, w164, w165);
            i016[e] = (unsigned short)i0;
        }
    }
    __threadfence();
    grid.sync();

    // ---------------- Phase 3: ownership-partitioned den partials ----------------
    {
        const int rn = (N + RANGES - 1) / RANGES;
        const int es = (E + SPLITS - 1) / SPLITS;
        for (int pair = blockIdx.x; pair < RANGES * SPLITS; pair += gridDim.x){
            const int r = pair & (RANGES - 1);
            const int s = pair >> 5;
            const int base = r * rn;

            __syncthreads();                 // prior pair's lden reads complete
            for (int i = tid; i < rn; i += BLK) lden[i] = 0.0f;
            __syncthreads();

            const int e0 = s * es;
            const int e1 = min(e0 + es, E);
            #pragma unroll 4
            for (int e = e0 + tid; e < e1; e += BLK){
                unsigned d = (unsigned)i016[e] - (unsigned)base;
                if (d < (unsigned)rn) atomicAdd(&lden[d], ex[e]);
            }
            __syncthreads();

            float* dp = den_part + (size_t)s * DP_STRIDE + base;
            for (int i = tid; i < rn && base + i < N; i += BLK) dp[i] = lden[i];
        }
    }
    __threadfence();
    grid.sync();

    // ---------------- Phase 4: collapse partials ----------------
    for (int i = blockIdx.x * BLK + tid; i < N; i += nthreads){
        float sum = 0.f;
        #pragma unroll
        for (int s = 0; s < SPLITS; s++) sum += den_part[(size_t)s * DP_STRIDE + i];
        den[i] = sum;
    }
    __threadfence();
    grid.sync();

    // ---------------- Phase 5: out = ex / den[i0] ----------------
    for (int e = blockIdx.x * BLK + tid; e < E; e += nthreads){
        out[e] = ex[e] / den[(int)i016[e]];
    }
}

// ================= fallback kernels (proven R6 path) =================
__global__ __launch_bounds__(256) void node_pack_kernel(
    const float* __restrict__ from_s, const float* __restrict__ from_v,
    const float* __restrict__ from_fr, const float* __restrict__ from_p,
    const float* __restrict__ to_s, const float* __restrict__ to_v,
    const float* __restrict__ to_fr, const float* __restrict__ to_p,
    const float* __restrict__ Wfs, const float* __restrict__ Wts,
    const float* __restrict__ Wfv, const float* __restrict__ Wtv,
    const float* __restrict__ Wattn,
    float* __restrict__ packA, float* __restrict__ packB,
    int N)
{
    const int side = blockIdx.y;
    const float* node_s = side ? to_s  : from_s;
    const float* node_v = side ? to_v  : from_v;
    const float* frame  = side ? to_fr : from_fr;
    const float* pos    = side ? to_p  : from_p;
    const float* Wsp    = side ? Wts   : Wfs;
    const float* Wvp    = side ? Wtv   : Wfv;
    const int    s_off  = side ? 32 : 0;
    const int    v_off  = side ? 115 : 64;
    float*       pack   = side ? packB : packA;

    __shared__ float smem[SMEM_FLOATS];
    float* lws = smem + OFF_LWS;
    float* lwv = smem + OFF_LWV;
    float* lwa = smem + OFF_LWA;
    float* ls  = smem + OFF_LS;
    float* lv  = smem + OFF_LV;
    float* lf  = smem + OFF_LF;
    float* lp  = smem + OFF_LP;

    const int tid = threadIdx.x;
    for (int i = tid; i < NHS * NS; i += 256) lws[(i / NS) * WS_PAD + (i % NS)] = Wsp[i];
    if (tid < NHV * NV) lwv[(tid / NV) * WV_PAD + (tid % NV)] = Wvp[tid];
    if (tid < NHS) lwa[tid] = Wattn[s_off + tid];
    if (tid < NHV * 3) lwa[NHS + tid] = Wattn[v_off + tid];

    const int nchunks = (N + NPB - 1) / NPB;
    for (int c = blockIdx.x; c < nchunks; c += gridDim.x){
        const int nbase = c * NPB;
        const int cnt = min(NPB, N - nbase);
        __syncthreads();
        {
            const float4* sp = (const float4*)(node_s + (size_t)nbase * NS);
            if (tid < cnt * (NS / 4)) ((float4*)ls)[tid] = sp[tid];
            const float4* vp = (const float4*)(node_v + (size_t)nbase * NV * 3);
            if (tid < cnt * (NV * 3 / 4)) ((float4*)lv)[tid] = vp[tid];
            if (tid < cnt * 9) lf[tid] = frame[(size_t)nbase * 9 + tid];
            if (tid < cnt * 3) lp[tid] = pos[(size_t)nbase * 3 + tid];
        }
        __syncthreads();
        node_pack_body(node_s, node_v, frame, pos, pack, N, nbase, cnt,
                       lws, lwv, lwa, ls, lv, lf, lp, tid);
    }
}

__global__ __launch_bounds__(256) void edge_fused_kernel(
    const int* __restrict__ idx,
    const float* __restrict__ packA, const float* __restrict__ packB,
    const float* __restrict__ Wattn,
    float* __restrict__ ex, unsigned short* __restrict__ i016, int E)
{
    int e = blockIdx.x * 256 + threadIdx.x;
    if (e >= E) return;
    int i0 = __builtin_nontemporal_load(idx + e);
    int i1 = __builtin_nontemporal_load(idx + E + e);
    ex[e] = edge_raw_exp(packA, packB, i0, i1,
                         Wattn[112], Wattn[113], Wattn[114],
                         Wattn[163], Wattn[164], Wattn[165]);
    i016[e] = (unsigned short)i0;
}

__global__ __launch_bounds__(512) void den_scan_kernel(
    const unsigned short* __restrict__ i016, const float* __restrict__ ex,
    float* __restrict__ den_part, int E, int N)
{
    const int r = blockIdx.x & (RANGES - 1);
    const int s = blockIdx.x >> 5;
    const int rn = (N + RANGES - 1) / RANGES;
    const int base = r * rn;

    extern __shared__ float lden[];
    for (int i = threadIdx.x; i < rn; i += 512) lden[i] = 0.0f;
    __syncthreads();

    const int es = (E + SPLITS - 1) / SPLITS;
    const int e0 = s * es;
    const int e1 = min(e0 + es, E);
    #pragma unroll 4
    for (int e = e0 + threadIdx.x; e < e1; e += 512){
        unsigned d = (unsigned)i016[e] - (unsigned)base;
        if (d < (unsigned)rn) atomicAdd(&lden[d], ex[e]);
    }
    __syncthreads();

    float* dp = den_part + (size_t)s * DP_STRIDE + base;
    for (int i = threadIdx.x; i < rn && base + i < N; i += 512) dp[i] = lden[i];
}

__global__ __launch_bounds__(256) void collapse_kernel(
    const float* __restrict__ den_part, float* __restrict__ den, int N)
{
    int i = blockIdx.x * 256 + threadIdx.x;
    if (i >= N) return;
    float sum = 0.f;
    #pragma unroll
    for (int s = 0; s < SPLITS; s++)
        sum += __builtin_nontemporal_load(den_part + (size_t)s * DP_STRIDE + i);
    den[i] = sum;
}

__global__ __launch_bounds__(256) void edge_out_kernel(
    const unsigned short* __restrict__ i016, const float* __restrict__ ex,
    const float* __restrict__ den, float* __restrict__ out, int E)
{
    int e = blockIdx.x * 256 + threadIdx.x;
    if (e >= E) return;
    int i0 = (int)__builtin_nontemporal_load(i016 + e);
    float v = __builtin_nontemporal_load(ex + e) / den[i0];
    __builtin_nontemporal_store(v, out + e);
}

extern "C" void kernel_launch(void* const* d_in, const int* in_sizes, int n_in,
                              void* d_out, int out_size, void* d_ws, size_t ws_size,
                              hipStream_t stream)
{
    const float* from_s  = (const float*)d_in[0];
    const float* from_v  = (const float*)d_in[1];
    const float* to_s    = (const float*)d_in[2];
    const float* to_v    = (const float*)d_in[3];
    const float* from_fr = (const float*)d_in[4];
    const float* to_fr   = (const float*)d_in[5];
    const float* from_p  = (const float*)d_in[6];
    const float* to_p    = (const float*)d_in[7];
    const float* Wfs     = (const float*)d_in[8];
    const float* Wts     = (const float*)d_in[9];
    const float* Wfv     = (const float*)d_in[10];
    const float* Wtv     = (const float*)d_in[11];
    const float* Wattn   = (const float*)d_in[12];
    const int*   idx     = (const int*)d_in[13];

    int N = in_sizes[0] / NS;
    int E = in_sizes[13] / 2;
    float* out = (float*)d_out;

    char* ws = (char*)d_ws;
    size_t packBytes = (size_t)N * 8 * sizeof(float);
    float*          packA    = (float*)(ws);
    float*          packB    = (float*)(ws + packBytes);
    float*          ex       = (float*)(ws + 2 * packBytes);
    float*          den_part = (float*)(ws + 2 * packBytes + (size_t)E * 4);
    float*          den      = (float*)(ws + 2 * packBytes + (size_t)E * 4
                                         + (size_t)SPLITS * DP_STRIDE * 4);
    unsigned short* i016     = (unsigned short*)(ws + 2 * packBytes + (size_t)E * 4
                                         + (size_t)SPLITS * DP_STRIDE * 4
                                         + (size_t)N * 4 + 256);

    // --- try cooperative mega-kernel with runtime-validated grid size ---
    int dev = 0;
    (void)hipGetDevice(&dev);
    int numCU = 0;
    (void)hipDeviceGetAttribute(&numCU, hipDeviceAttributeMultiprocessorCount, dev);
    int maxBlkPerCU = 0;
    hipError_t occ = hipOccupancyMaxActiveBlocksPerMultiprocessor(
        &maxBlkPerCU, (const void*)mega_kernel, BLK, 0);

    hipError_t err = hipErrorUnknown;
    if (occ == hipSuccess && numCU > 0 && maxBlkPerCU > 0){
        int grid = maxBlkPerCU * numCU;
        if (grid > MAXGRID) grid = MAXGRID;
        grid &= ~1;                                   // even (side split)
        if (grid >= 64){
            void* args[] = {
                (void*)&from_s, (void*)&from_v, (void*)&to_s, (void*)&to_v,
                (void*)&from_fr, (void*)&to_fr, (void*)&from_p, (void*)&to_p,
                (void*)&Wfs, (void*)&Wts, (void*)&Wfv, (void*)&Wtv,
                (void*)&Wattn, (void*)&idx,
                (void*)&packA, (void*)&packB, (void*)&ex, (void*)&den_part,
                (void*)&den, (void*)&i016, (void*)&out, (void*)&N, (void*)&E
            };
            err = hipLaunchCooperativeKernel((void*)mega_kernel, dim3(grid), dim3(BLK),
                                             args, 0, stream);
        }
    }

    if (err != hipSuccess){
        (void)hipGetLastError();                      // clear sticky error
        // --- fallback: proven 5-kernel path ---
        dim3 ngrid(768, 2);
        node_pack_kernel<<<ngrid, 256, 0, stream>>>(
            from_s, from_v, from_fr, from_p,
            to_s, to_v, to_fr, to_p,
            Wfs, Wts, Wfv, Wtv, Wattn,
            packA, packB, N);

        int nb_e = (E + 255) / 256;
        edge_fused_kernel<<<nb_e, 256, 0, stream>>>(idx, packA, packB, Wattn, ex, i016, E);

        int rn = (N + RANGES - 1) / RANGES;
        size_t lds_bytes = (size_t)rn * sizeof(float);
        den_scan_kernel<<<RANGES * SPLITS, 512, lds_bytes, stream>>>(i016, ex, den_part, E, N);
        collapse_kernel<<<(N + 255) / 256, 256, 0, stream>>>(den_part, den, N);
        edge_out_kernel<<<nb_e, 256, 0, stream>>>(i016, ex, den, out, E);
    }
}

// Round 10
// 80.002 us; speedup vs baseline: 9.1504x; 9.1504x over previous
//
#include <hip/hip_runtime.h>
#include <hip/hip_fp16.h>
#include <math.h>

#define NS 64
#define NV 16
#define NHS 32
#define NHV 16
#define NPB 16           // nodes per chunk in node_pack (16 lanes/node, 256 threads)
#define NPGRID 768       // persistent blocks per side in node_pack
#define WS_PAD 68        // padded row stride for Ws in LDS (breaks bank conflict)
#define WV_PAD 17

// den_scan geometry: grid = RANGES*SPLITS blocks of 512 threads.
// s in LOW bits: the RANGES blocks sharing edge-slice s are blockIdx = r*SPLITS+s,
// stride 32 == 0 (mod 8 XCDs) -> same XCD -> slice cached in that XCD's L2.
#define RANGES 8         // node ranges (one LDS den per range); rn = 6250 -> 25KB LDS
#define SPLITS 32        // edge-list splits
#define DP_STRIDE 50176  // padded per-split den stride (>= N, mult of 256)

__device__ __forceinline__ float silu_f(float x){ return x * (1.0f / (1.0f + __expf(-x))); }

__device__ __forceinline__ float packh2(float a, float b){
    __half2 h = __floats2half2_rn(a, b);
    return __uint_as_float(*(unsigned*)&h);
}
__device__ __forceinline__ float2 unpackh2(float w){
    __half2 h = *(__half2*)&w;
    return __half22float2(h);
}

// Per-node precompute: pack[n] = 32B = {A fp32, ff[9]+pos[3] as fp16}
// Persistent: weights -> LDS once, then grid-stride over node chunks.
__global__ __launch_bounds__(256) void node_pack_kernel(
    const float* __restrict__ from_s, const float* __restrict__ from_v,
    const float* __restrict__ from_fr, const float* __restrict__ from_p,
    const float* __restrict__ to_s, const float* __restrict__ to_v,
    const float* __restrict__ to_fr, const float* __restrict__ to_p,
    const float* __restrict__ Wfs, const float* __restrict__ Wts,
    const float* __restrict__ Wfv, const float* __restrict__ Wtv,
    const float* __restrict__ Wattn,
    float* __restrict__ packA, float* __restrict__ packB,
    int N)
{
    const int side = blockIdx.y;
    const float* node_s = side ? to_s  : from_s;
    const float* node_v = side ? to_v  : from_v;
    const float* frame  = side ? to_fr : from_fr;
    const float* pos    = side ? to_p  : from_p;
    const float* Ws     = side ? Wts   : Wfs;
    const float* Wv     = side ? Wtv   : Wfv;
    const int    s_off  = side ? 32 : 0;
    const int    v_off  = side ? 115 : 64;
    float*       pack   = side ? packB : packA;

    __shared__ float lws[NHS * WS_PAD];
    __shared__ float lwv[NHV * WV_PAD];
    __shared__ float lwa[NHS + NHV * 3];
    __shared__ float ls[NPB * NS];
    __shared__ float lv[NPB * NV * 3];
    __shared__ float lf[NPB * 9];
    __shared__ float lp[NPB * 3];

    const int tid = threadIdx.x;
    // weights -> LDS exactly once per block
    for (int i = tid; i < NHS * NS; i += 256) lws[(i / NS) * WS_PAD + (i % NS)] = Ws[i];
    if (tid < NHV * NV) lwv[(tid / NV) * WV_PAD + (tid % NV)] = Wv[tid];
    if (tid < NHS) lwa[tid] = Wattn[s_off + tid];
    if (tid < NHV * 3) lwa[NHS + tid] = Wattn[v_off + tid];

    const int g = tid >> 4;
    const int l = tid & 15;
    const int nchunks = (N + NPB - 1) / NPB;

    for (int c = blockIdx.x; c < nchunks; c += NPGRID){
        const int nbase = c * NPB;
        const int cnt = min(NPB, N - nbase);
        __syncthreads();                          // LDS reuse barrier
        {
            const float4* sp = (const float4*)(node_s + (size_t)nbase * NS);
            if (tid < cnt * (NS / 4)) ((float4*)ls)[tid] = sp[tid];
            const float4* vp = (const float4*)(node_v + (size_t)nbase * NV * 3);
            if (tid < cnt * (NV * 3 / 4)) ((float4*)lv)[tid] = vp[tid];
            if (tid < cnt * 9) lf[tid] = frame[(size_t)nbase * 9 + tid];
            if (tid < cnt * 3) lp[tid] = pos[(size_t)nbase * 3 + tid];
        }
        __syncthreads();                          // also publishes weights on 1st iter

        if (g < cnt){
            const int n = nbase + g;

            const float4* sg = (const float4*)(ls + g * NS);
            float d0 = 0.f, d1 = 0.f;
            #pragma unroll
            for (int k4 = 0; k4 < NS / 4; k4++){
                float4 sv = sg[k4];
                float4 w0 = *(const float4*)(lws + l * WS_PAD + k4 * 4);
                float4 w1 = *(const float4*)(lws + (l + 16) * WS_PAD + k4 * 4);
                d0 += sv.x * w0.x + sv.y * w0.y + sv.z * w0.z + sv.w * w0.w;
                d1 += sv.x * w1.x + sv.y * w1.y + sv.z * w1.z + sv.w * w1.w;
            }
            float acc = silu_f(d0) * lwa[l] + silu_f(d1) * lwa[l + 16];

            float a0 = 0.f, a1 = 0.f, a2 = 0.f;
            const float* vg = lv + g * NV * 3;
            #pragma unroll
            for (int vv = 0; vv < NV; vv++){
                float w = lwv[l * WV_PAD + vv];
                a0 += vg[vv * 3 + 0] * w;
                a1 += vg[vv * 3 + 1] * w;
                a2 += vg[vv * 3 + 2] * w;
            }
            const float* ff = lf + g * 9;
            #pragma unroll
            for (int c3 = 0; c3 < 3; c3++){
                float t = a0 * ff[c3] + a1 * ff[3 + c3] + a2 * ff[6 + c3];
                acc += silu_f(t) * lwa[NHS + l * 3 + c3];
            }

            acc += __shfl_xor(acc, 8, 16);
            acc += __shfl_xor(acc, 4, 16);
            acc += __shfl_xor(acc, 2, 16);
            acc += __shfl_xor(acc, 1, 16);

            if (l < 2){
                const float* ps = lp + g * 3;
                float4 o;
                if (l == 0){
                    o = make_float4(acc,
                                    packh2(ff[0], ff[1]),
                                    packh2(ff[2], ff[3]),
                                    packh2(ff[4], ff[5]));
                } else {
                    o = make_float4(packh2(ff[6], ff[7]),
                                    packh2(ff[8], ps[0]),
                                    packh2(ps[1], ps[2]),
                                    0.0f);
                }
                ((float4*)(pack + (size_t)n * 8))[l] = o;
            }
        }
    }
}

// Fused: raw -> exp -> ex[] ; also emits u16 copy of idx0. NO atomics.
__global__ __launch_bounds__(256) void edge_fused_kernel(
    const int* __restrict__ idx,
    const float* __restrict__ packA,
    const float* __restrict__ packB,
    const float* __restrict__ Wattn,
    float* __restrict__ ex,
    unsigned short* __restrict__ i016,
    int E)
{
    int e = blockIdx.x * 256 + threadIdx.x;
    if (e >= E) return;
    int i0 = __builtin_nontemporal_load(idx + e);
    int i1 = __builtin_nontemporal_load(idx + E + e);
    const float4* pa = (const float4*)(packA + (size_t)i0 * 8);
    const float4* pb = (const float4*)(packB + (size_t)i1 * 8);
    float4 a0 = pa[0], a1 = pa[1];
    float4 b0 = pb[0], b1 = pb[1];

    float2 t;
    t = unpackh2(a0.y); float af0 = t.x, af1 = t.y;
    t = unpackh2(a0.z); float af2 = t.x, af3 = t.y;
    t = unpackh2(a0.w); float af4 = t.x, af5 = t.y;
    t = unpackh2(a1.x); float af6 = t.x, af7 = t.y;
    t = unpackh2(a1.y); float af8 = t.x, ap0 = t.y;
    t = unpackh2(a1.z); float ap1 = t.x, ap2 = t.y;
    t = unpackh2(b0.y); float bf0 = t.x, bf1 = t.y;
    t = unpackh2(b0.z); float bf2 = t.x, bf3 = t.y;
    t = unpackh2(b0.w); float bf4 = t.x, bf5 = t.y;
    t = unpackh2(b1.x); float bf6 = t.x, bf7 = t.y;
    t = unpackh2(b1.y); float bf8 = t.x, bp0 = t.y;
    t = unpackh2(b1.z); float bp1 = t.x, bp2 = t.y;

    float d0 = bp0 - ap0, d1 = bp1 - ap1, d2 = bp2 - ap2;
    float pdf0 = d0*af0 + d1*af3 + d2*af6;
    float pdf1 = d0*af1 + d1*af4 + d2*af7;
    float pdf2 = d0*af2 + d1*af5 + d2*af8;
    float pdt0 = -(d0*bf0 + d1*bf3 + d2*bf6);
    float pdt1 = -(d0*bf1 + d1*bf4 + d2*bf7);
    float pdt2 = -(d0*bf2 + d1*bf5 + d2*bf8);

    float r = a0.x + b0.x;
    r += silu_f(pdf0) * Wattn[112] + silu_f(pdf1) * Wattn[113] + silu_f(pdf2) * Wattn[114];
    r += silu_f(pdt0) * Wattn[163] + silu_f(pdt1) * Wattn[164] + silu_f(pdt2) * Wattn[165];

    ex[e] = __expf(r);
    i016[e] = (unsigned short)i0;
}

// Ownership-partitioned segmented sum. Block (r, s): scans edge-slice s,
// LDS-accumulates nodes in range r, writes a non-atomic partial.
__global__ __launch_bounds__(512) void den_scan_kernel(
    const unsigned short* __restrict__ i016,
    const float* __restrict__ ex,
    float* __restrict__ den_part,     // [SPLITS][DP_STRIDE]
    int E, int N)
{
    const int s = blockIdx.x & (SPLITS - 1);   // low bits: XCD-affine slice reuse
    const int r = blockIdx.x / SPLITS;
    const int rn = (N + RANGES - 1) / RANGES;  // 6250 for N=50000
    const int base = r * rn;

    extern __shared__ float lden[];            // rn floats (25KB)
    for (int i = threadIdx.x; i < rn; i += 512) lden[i] = 0.0f;
    __syncthreads();

    const int es = (E + SPLITS - 1) / SPLITS;
    const int e0 = s * es;
    const int e1 = min(e0 + es, E);

    #pragma unroll 4
    for (int e = e0 + threadIdx.x; e < e1; e += 512){
        unsigned d = (unsigned)i016[e] - (unsigned)base;
        if (d < (unsigned)rn){
            atomicAdd(&lden[d], ex[e]);        // LDS atomic: fast HW path
        }
    }
    __syncthreads();

    float* dp = den_part + (size_t)s * DP_STRIDE + base;
    for (int i = threadIdx.x; i < rn && base + i < N; i += 512) dp[i] = lden[i];
}

// collapse the SPLITS partial sums; store reciprocal so edge_out multiplies
__global__ __launch_bounds__(256) void collapse_kernel(
    const float* __restrict__ den_part,
    float* __restrict__ inv_den,
    int N)
{
    int i = blockIdx.x * 256 + threadIdx.x;
    if (i >= N) return;
    float sum = 0.f;
    #pragma unroll
    for (int s = 0; s < SPLITS; s++)
        sum += __builtin_nontemporal_load(den_part + (size_t)s * DP_STRIDE + i);
    inv_den[i] = 1.0f / sum;
}

__global__ __launch_bounds__(256) void edge_out_kernel(
    const unsigned short* __restrict__ i016,
    const float* __restrict__ ex,
    const float* __restrict__ inv_den,
    float* __restrict__ out,
    int E)
{
    int e = blockIdx.x * 256 + threadIdx.x;
    if (e >= E) return;
    int i0 = (int)__builtin_nontemporal_load(i016 + e);
    float v = __builtin_nontemporal_load(ex + e) * inv_den[i0];
    __builtin_nontemporal_store(v, out + e);
}

extern "C" void kernel_launch(void* const* d_in, const int* in_sizes, int n_in,
                              void* d_out, int out_size, void* d_ws, size_t ws_size,
                              hipStream_t stream)
{
    const float* from_s  = (const float*)d_in[0];
    const float* from_v  = (const float*)d_in[1];
    const float* to_s    = (const float*)d_in[2];
    const float* to_v    = (const float*)d_in[3];
    const float* from_fr = (const float*)d_in[4];
    const float* to_fr   = (const float*)d_in[5];
    const float* from_p  = (const float*)d_in[6];
    const float* to_p    = (const float*)d_in[7];
    const float* Wfs     = (const float*)d_in[8];
    const float* Wts     = (const float*)d_in[9];
    const float* Wfv     = (const float*)d_in[10];
    const float* Wtv     = (const float*)d_in[11];
    const float* Wattn   = (const float*)d_in[12];
    const int*   idx     = (const int*)d_in[13];

    int N = in_sizes[0] / NS;
    int E = in_sizes[13] / 2;
    float* out = (float*)d_out;

    char* ws = (char*)d_ws;
    size_t packBytes = (size_t)N * 8 * sizeof(float);
    float*          packA    = (float*)(ws);
    float*          packB    = (float*)(ws + packBytes);
    float*          ex       = (float*)(ws + 2 * packBytes);
    float*          den_part = (float*)(ws + 2 * packBytes + (size_t)E * 4);
    float*          inv_den  = (float*)(ws + 2 * packBytes + (size_t)E * 4
                                         + (size_t)SPLITS * DP_STRIDE * 4);
    unsigned short* i016     = (unsigned short*)(ws + 2 * packBytes + (size_t)E * 4
                                         + (size_t)SPLITS * DP_STRIDE * 4
                                         + (size_t)N * 4 + 256);

    dim3 ngrid(NPGRID, 2);
    node_pack_kernel<<<ngrid, 256, 0, stream>>>(
        from_s, from_v, from_fr, from_p,
        to_s, to_v, to_fr, to_p,
        Wfs, Wts, Wfv, Wtv, Wattn,
        packA, packB, N);

    int nb_e = (E + 255) / 256;
    edge_fused_kernel<<<nb_e, 256, 0, stream>>>(idx, packA, packB, Wattn, ex, i016, E);

    int rn = (N + RANGES - 1) / RANGES;
    size_t lds_bytes = (size_t)rn * sizeof(float);
    den_scan_kernel<<<RANGES * SPLITS, 512, lds_bytes, stream>>>(i016, ex, den_part, E, N);
    collapse_kernel<<<(N + 255) / 256, 256, 0, stream>>>(den_part, inv_den, N);
    edge_out_kernel<<<nb_e, 256, 0, stream>>>(i016, ex, inv_den, out, E);
}